// Round 8
// baseline (4481.152 us; speedup 1.0000x reference)
//
#include <hip/hip_runtime.h>
#include <cstdint>
#include <cstddef>

// SNN pipeline, round 17:
//  k1: unchanged from round 10.
//  k2: BARRIER-FREE, LDS-FREE. r9-r16 invariant: dur x MfmaUtil == 1350 us in
//      every schedule variant (53-59%); per-wave serial chain (read+unpack 480
//      + MFMA 776 cyc) = 62% duty, and the per-tile barrier phase-locks all
//      waves into the same idle window. Fix: each wave loads its OWN fragments
//      (A 2xb128 from s1bits/L3, B 4xb128 both Dekker planes from w2d/L2)
//      straight to REGISTERS, named cur/nxt double-buffer (#pragma unroll 2),
//      prefetch issued one full tile (~1000cyc) ahead -> covers L3 latency.
//      No __shared__, no barriers, no DMA: waves free-run and de-phase, MFMA
//      pipe fed continuously. Bytes per fragment identical to the old LDS
//      slots -> bit-identical MFMA stream -> absmax must stay 0.0234375.
//      Ballot epilogue unchanged (r16: u16 col-spike-masks, no cross-lane).
//  k3: unchanged (mask->wo dot, ascending cols).
// ws: w2d 4MiB @0 | s1bits 128MiB @16MiB | po32 masks 80MiB @160MiB

typedef _Float16 f16;
typedef _Float16 f16x8 __attribute__((ext_vector_type(8)));
typedef float f32x4 __attribute__((ext_vector_type(4)));
typedef int i32x4 __attribute__((ext_vector_type(4)));
typedef unsigned int u32;

#define MFMA16(A, B, C) __builtin_amdgcn_mfma_f32_16x16x32_f16(A, B, C, 0, 0, 0)

static constexpr int BSZ = 65536;
static constexpr int IN = 512;
static constexpr int H = 1024;

// W2[k][j] fp32 -> w2d[plane][j][k] f16 Dekker limbs: plane0 = f16(w),
// plane1 = f16((w - hi) * 2^11).
__global__ void prep_dekker(const float* __restrict__ src, f16* __restrict__ dst) {
    int idx = blockIdx.x * 256 + threadIdx.x;
    int k = idx >> 10;
    int j = idx & 1023;
    float w = src[(size_t)k * 1024 + j];
    f16 hi = (f16)w;
    float lo = (w - (float)hi) * 2048.0f;
    size_t o = (size_t)j * 1024 + k;
    dst[o] = hi;
    dst[o + (size_t)H * H] = (f16)lo;
}

// k1: fp32 k-ordered FMA-chain GEMM (BLAS-replica) + fp32-replica LIF -> masks.
// tile 128 b-rows x 256 h-cols, 256 threads = 16 ht x 16 bt, thread = 8b x 16h.
__global__ __launch_bounds__(256, 2) void k1_chain(
    const float* __restrict__ x, const float* __restrict__ w1,
    const float* __restrict__ b1, unsigned short* __restrict__ s1b) {
    __shared__ float xs[32][132];   // [k][b]; stride 132: rows 16B-aligned, banks spread
    __shared__ float ws[32][256];   // [k][h]
    const int hblk = blockIdx.x;    // 4
    const int bblk = blockIdx.y;    // 512
    const int tid = threadIdx.x;
    const int ht = tid & 15, bt = tid >> 4;
    const int h0 = hblk * 256, b0 = bblk * 128;

    float acc[8][16] = {};

    float4 xv[4], wv[8];
#pragma unroll
    for (int i = 0; i < 4; ++i) {
        int idx = tid + 256 * i;            // 1024 f4: 128 rows x 8 segs
        int br = idx >> 3, ks = idx & 7;
        xv[i] = *(const float4*)&x[(size_t)(b0 + br) * IN + ks * 4];
    }
#pragma unroll
    for (int i = 0; i < 8; ++i) {
        int idx = tid + 256 * i;            // 2048 f4: 32 rows x 64 segs
        int kr = idx >> 6, c4 = idx & 63;
        wv[i] = *(const float4*)&w1[(size_t)kr * H + h0 + c4 * 4];
    }

    for (int kc = 0; kc < 512; kc += 32) {
        __syncthreads();                    // prev compute's LDS reads done
#pragma unroll
        for (int i = 0; i < 4; ++i) {
            int idx = tid + 256 * i;
            int br = idx >> 3, ks = idx & 7;
            xs[ks * 4 + 0][br] = xv[i].x;
            xs[ks * 4 + 1][br] = xv[i].y;
            xs[ks * 4 + 2][br] = xv[i].z;
            xs[ks * 4 + 3][br] = xv[i].w;
        }
#pragma unroll
        for (int i = 0; i < 8; ++i) {
            int idx = tid + 256 * i;
            int kr = idx >> 6, c4 = idx & 63;
            *(float4*)&ws[kr][c4 * 4] = wv[i];
        }
        __syncthreads();
        int kn = (kc + 32) & 511;           // wraps to 0 on last chunk (dummy)
#pragma unroll
        for (int i = 0; i < 4; ++i) {
            int idx = tid + 256 * i;
            int br = idx >> 3, ks = idx & 7;
            xv[i] = *(const float4*)&x[(size_t)(b0 + br) * IN + kn + ks * 4];
        }
#pragma unroll
        for (int i = 0; i < 8; ++i) {
            int idx = tid + 256 * i;
            int kr = idx >> 6, c4 = idx & 63;
            wv[i] = *(const float4*)&w1[(size_t)(kn + kr) * H + h0 + c4 * 4];
        }
#pragma unroll 2
        for (int k = 0; k < 32; ++k) {
            float xr[8];
            *(float4*)&xr[0] = *(const float4*)&xs[k][bt * 8];
            *(float4*)&xr[4] = *(const float4*)&xs[k][bt * 8 + 4];
            float wr[16];
#pragma unroll
            for (int g = 0; g < 4; ++g)
                *(float4*)&wr[g * 4] = *(const float4*)&ws[k][ht * 4 + 64 * g];
#pragma unroll
            for (int i = 0; i < 8; ++i)
#pragma unroll
                for (int j = 0; j < 16; ++j)
                    acc[i][j] = fmaf(xr[i], wr[j], acc[i][j]);  // strict k-order chain
        }
    }

    float b1v[16];
#pragma unroll
    for (int g = 0; g < 4; ++g)
#pragma unroll
        for (int m = 0; m < 4; ++m)
            b1v[g * 4 + m] = b1[h0 + g * 64 + ht * 4 + m];
#pragma unroll
    for (int i = 0; i < 8; ++i) {
        unsigned short outb[16];
#pragma unroll
        for (int j = 0; j < 16; ++j) {
            float c = __fadd_rn(acc[i][j], b1v[j]);
            float m = 0.0f;
            unsigned bits = 0u;
#pragma unroll
            for (int t = 0; t < 10; ++t) {
                float rst = (m > 1.0f) ? 1.0f : 0.0f;
                m = __fmul_rn(0.9f, m);
                m = __fadd_rn(m, c);
                m = __fsub_rn(m, rst);
                if (m > 1.0f) bits |= (1u << t);
            }
            outb[j] = (unsigned short)bits;
        }
        size_t row = (size_t)(b0 + bt * 8 + i);
#pragma unroll
        for (int g = 0; g < 4; ++g)
            *(int2*)&s1b[row * H + h0 + g * 64 + ht * 4] = ((const int2*)outb)[g];
    }
}

// k2: spike GEMM, barrier-free. Block = 64 rows x 32 cols, 512 threads = 8
// independent waves: wave = (strip = w&3) x (colfrag = w>>2); each wave owns
// all 10 timesteps of its 16 rows x 16 cols, loads its own fragments global->
// registers, double-buffered. Ballot epilogue -> u16 spike masks.
__global__ __launch_bounds__(512, 2) void k2_spikes_gemm(
    const unsigned short* __restrict__ s1bits, const f16* __restrict__ w2d,
    const float* __restrict__ b2, u32* __restrict__ po32) {
    const int jblk = blockIdx.x, bblk = blockIdx.y;
    const int tid = threadIdx.x;
    const int lane = tid & 63, wave = tid >> 6;
    const int strip = wave & 3, cfw = wave >> 2;
    const int l15 = lane & 15, loct = lane >> 4;

    // per-lane fragment sources (identical bytes to the old LDS slots):
    // A: row = strip*16+l15 of s1bits, 16B at k-offset loct*8 (+32 for kch1)
    // B: col = jblk*32+cfw*16+l15 of w2d plane p, same k-offsets
    const unsigned short* gA =
        s1bits + (size_t)(bblk * 64 + strip * 16 + l15) * 1024 + loct * 8;
    const f16* gB0 = w2d + (size_t)(jblk * 32 + cfw * 16 + l15) * 1024 + loct * 8;
    const f16* gB1 = gB0 + (size_t)H * H;

    f32x4 acc[10][2] = {};   // [tt][plane] = 80 acc regs

    typedef union { i32x4 i; unsigned long long u[2]; f16x8 h; } U;

    // named cur/nxt register tiles (no runtime indexing -> no scratch)
    i32x4 a0c = *(const i32x4*)(gA);
    i32x4 a1c = *(const i32x4*)(gA + 32);
    i32x4 b00c = *(const i32x4*)(gB0);        // plane0 kch0
    i32x4 b01c = *(const i32x4*)(gB0 + 32);   // plane0 kch1
    i32x4 b10c = *(const i32x4*)(gB1);        // plane1 kch0
    i32x4 b11c = *(const i32x4*)(gB1 + 32);   // plane1 kch1

#pragma unroll 2
    for (int t = 0; t < 16; ++t) {
        const int kn = ((t + 1) * 64) & 1023;   // wraps to 0 on last iter (dummy)
        // prefetch tile t+1 into the nxt set; issued ~1000 cyc before use.
        i32x4 a0n = *(const i32x4*)(gA + kn);
        i32x4 a1n = *(const i32x4*)(gA + kn + 32);
        i32x4 b00n = *(const i32x4*)(gB0 + kn);
        i32x4 b01n = *(const i32x4*)(gB0 + kn + 32);
        i32x4 b10n = *(const i32x4*)(gB1 + kn);
        i32x4 b11n = *(const i32x4*)(gB1 + kn + 32);
        // kch 0
        {
            U m; m.i = a0c;
            U p0; p0.i = b00c;
            U p1; p1.i = b10c;
            f16x8 bf0 = p0.h, bf1 = p1.h;
            __builtin_amdgcn_s_setprio(1);
#pragma unroll
            for (int tt = 0; tt < 10; ++tt) {
                const int sh = 10 - tt;
                U r;
                r.u[0] = (m.u[0] << sh) & 0x0400040004000400ULL;
                r.u[1] = (m.u[1] << sh) & 0x0400040004000400ULL;
                acc[tt][0] = MFMA16(r.h, bf0, acc[tt][0]);
                acc[tt][1] = MFMA16(r.h, bf1, acc[tt][1]);
            }
            __builtin_amdgcn_s_setprio(0);
        }
        // kch 1
        {
            U m; m.i = a1c;
            U p0; p0.i = b01c;
            U p1; p1.i = b11c;
            f16x8 bf0 = p0.h, bf1 = p1.h;
            __builtin_amdgcn_s_setprio(1);
#pragma unroll
            for (int tt = 0; tt < 10; ++tt) {
                const int sh = 10 - tt;
                U r;
                r.u[0] = (m.u[0] << sh) & 0x0400040004000400ULL;
                r.u[1] = (m.u[1] << sh) & 0x0400040004000400ULL;
                acc[tt][0] = MFMA16(r.h, bf0, acc[tt][0]);
                acc[tt][1] = MFMA16(r.h, bf1, acc[tt][1]);
            }
            __builtin_amdgcn_s_setprio(0);
        }
        a0c = a0n; a1c = a1n;
        b00c = b00n; b01c = b01n; b10c = b10n; b11c = b11n;
    }

    // epilogue: Dekker combine in f64 (guards near-threshold spikes),
    // fp32-replica LIF-2 (ops bit-identical), then __ballot -> u16
    // col-spike-mask per (tt, row). po32 word [jblk][tt][row]: lo u16 = cfw0
    // cols, hi u16 = cfw1 cols. Each halfword written exactly once.
    int col0 = jblk * 32 + cfw * 16 + l15;
    float b2v = b2[col0];
    float m2[4] = {0.0f, 0.0f, 0.0f, 0.0f};
    unsigned short* pw = (unsigned short*)po32;

#pragma unroll
    for (int tt = 0; tt < 10; ++tt) {
#pragma unroll
        for (int r = 0; r < 4; ++r) {
            float iv = (float)((double)acc[tt][0][r] * 16384.0 + (double)acc[tt][1][r] * 8.0);
            iv = __fadd_rn(iv, b2v);
            float rst = (m2[r] > 1.0f) ? 1.0f : 0.0f;
            m2[r] = __fmul_rn(0.9f, m2[r]);
            m2[r] = __fadd_rn(m2[r], iv);
            m2[r] = __fsub_rn(m2[r], rst);
            unsigned long long bal = __ballot(m2[r] > 1.0f);
            if (l15 == r) {
                int row = bblk * 64 + strip * 16 + loct * 4 + r;
                pw[(((size_t)jblk * 10 + tt) * BSZ + row) * 2 + cfw] =
                    (unsigned short)(bal >> (loct * 16));
            }
        }
    }
}

// k3: mask->wo dot in ascending column order + fp32-replica LIF-out, mean.
// Per b-row: 320 coalesced u32 mask loads; per mask 32 predicated f32 adds
// with the wo 32-chunk held in registers (staged via LDS broadcast).
__global__ __launch_bounds__(256) void k3_out(
    const u32* __restrict__ po32, const float* __restrict__ wo,
    const float* __restrict__ bo, float* __restrict__ out) {
    __shared__ float wos[1024];
    const int tid = threadIdx.x;
    for (int i = tid; i < 1024; i += 256) wos[i] = wo[i];
    __syncthreads();
    const int b = blockIdx.x * 256 + tid;

    float inp[10] = {};
    for (int jb = 0; jb < 32; ++jb) {
        float wr[32];
#pragma unroll
        for (int g = 0; g < 8; ++g)
            *(float4*)&wr[g * 4] = *(const float4*)&wos[jb * 32 + g * 4];
#pragma unroll
        for (int t = 0; t < 10; ++t) {
            u32 mk = po32[((size_t)jb * 10 + t) * BSZ + b];
#pragma unroll
            for (int bit = 0; bit < 32; ++bit)
                inp[t] += ((mk >> bit) & 1u) ? wr[bit] : 0.0f;
        }
    }

    float bov = bo[0];
    float mo = 0.0f, s = 0.0f;
#pragma unroll
    for (int t = 0; t < 10; ++t) {
        float iv = __fadd_rn(inp[t], bov);
        float rst = (mo > 1.0f) ? 1.0f : 0.0f;
        mo = __fmul_rn(0.9f, mo);
        mo = __fadd_rn(mo, iv);
        mo = __fsub_rn(mo, rst);
        s += mo;
    }
    out[b] = s / 10.0f;
}

extern "C" void kernel_launch(void* const* d_in, const int* in_sizes, int n_in,
                              void* d_out, int out_size, void* d_ws, size_t ws_size,
                              hipStream_t stream) {
    (void)in_sizes; (void)n_in; (void)out_size; (void)ws_size;
    const float* x  = (const float*)d_in[0];
    const float* W1 = (const float*)d_in[1];
    const float* b1 = (const float*)d_in[2];
    const float* W2 = (const float*)d_in[3];
    const float* b2 = (const float*)d_in[4];
    const float* Wo = (const float*)d_in[5];
    const float* bo = (const float*)d_in[6];
    float* out = (float*)d_out;

    char* ws = (char*)d_ws;
    f16* w2d = (f16*)ws;                                                   // 4 MiB @ 0
    unsigned short* s1bits = (unsigned short*)(ws + ((size_t)16 << 20));   // 128 MiB
    u32* po32 = (u32*)(ws + ((size_t)160 << 20));                          // 80 MiB

    prep_dekker<<<dim3((H * H) / 256), 256, 0, stream>>>(W2, w2d);
    k1_chain<<<dim3(4, BSZ / 128), 256, 0, stream>>>(x, W1, b1, s1bits);
    k2_spikes_gemm<<<dim3(H / 32, BSZ / 64), 512, 0, stream>>>(s1bits, w2d, b2, po32);
    k3_out<<<dim3(BSZ / 256), 256, 0, stream>>>(po32, Wo, bo, out);
}